// Round 1
// baseline (6509.801 us; speedup 1.0000x reference)
//
#include <hip/hip_runtime.h>
#include <hip/hip_bf16.h>
#include <math.h>

#define MDIM 2048
#define KDIM 1024
#define BIGF 1e9f

// ---------------- row normalization: one wave per row ----------------
__global__ __launch_bounds__(256) void normalize_rows(
    const float* __restrict__ x, const float* __restrict__ y,
    float* __restrict__ xn, float* __restrict__ yn) {
  int wave = (blockIdx.x * blockDim.x + threadIdx.x) >> 6;
  int lane = threadIdx.x & 63;
  const float* src;
  float* dst;
  int row;
  if (wave < MDIM) { src = x; dst = xn; row = wave; }
  else             { src = y; dst = yn; row = wave - MDIM; }
  const float* r = src + (size_t)row * KDIM;
  float* w = dst + (size_t)row * KDIM;
  float ss = 0.f;
  for (int c = lane * 4; c < KDIM; c += 64 * 4) {
    float4 v = *(const float4*)&r[c];
    ss += v.x * v.x + v.y * v.y + v.z * v.z + v.w * v.w;
  }
  #pragma unroll
  for (int off = 32; off; off >>= 1) ss += __shfl_xor(ss, off, 64);
  float inv = 1.f / fmaxf(sqrtf(ss), 1e-12f);
  for (int c = lane * 4; c < KDIM; c += 64 * 4) {
    float4 v = *(const float4*)&r[c];
    float4 o = {v.x * inv, v.y * inv, v.z * inv, v.w * inv};
    *(float4*)&w[c] = o;
  }
}

// ---------------- cost GEMM: C[i][j] = 1 - dot(A_i, B_j) ----------------
// A,B row-major (2048 x 1024). Tile 64x64, block 256 threads, 4x4 microtile.
__global__ __launch_bounds__(256) void gemm_cost(
    const float* __restrict__ xn, const float* __restrict__ yn,
    float* __restrict__ cost_base) {
  int z = blockIdx.z;
  const float* A = (z == 2) ? yn : xn;
  const float* B = (z == 0) ? yn : ((z == 1) ? xn : yn);
  float* C = cost_base + (size_t)z * MDIM * MDIM;

  __shared__ float As[16][64];
  __shared__ float Bs[16][64];

  int tid = threadIdx.x;
  int lrow = tid >> 2;        // 0..63 (tile row for loads)
  int lkc  = (tid & 3) * 4;   // 0,4,8,12 (k offset for loads)
  int m0 = (tid >> 4) * 4;    // 0..60
  int n0 = (tid & 15) * 4;    // 0..60

  float acc[4][4] = {};
  size_t arow = (size_t)(blockIdx.y * 64 + lrow) * KDIM;
  size_t brow = (size_t)(blockIdx.x * 64 + lrow) * KDIM;

  for (int k0 = 0; k0 < KDIM; k0 += 16) {
    float4 a = *(const float4*)&A[arow + k0 + lkc];
    float4 b = *(const float4*)&B[brow + k0 + lkc];
    __syncthreads();
    As[lkc + 0][lrow] = a.x; As[lkc + 1][lrow] = a.y;
    As[lkc + 2][lrow] = a.z; As[lkc + 3][lrow] = a.w;
    Bs[lkc + 0][lrow] = b.x; Bs[lkc + 1][lrow] = b.y;
    Bs[lkc + 2][lrow] = b.z; Bs[lkc + 3][lrow] = b.w;
    __syncthreads();
    #pragma unroll
    for (int k = 0; k < 16; ++k) {
      float4 av = *(const float4*)&As[k][m0];
      float4 bv = *(const float4*)&Bs[k][n0];
      float am[4] = {av.x, av.y, av.z, av.w};
      float bn[4] = {bv.x, bv.y, bv.z, bv.w};
      #pragma unroll
      for (int mi = 0; mi < 4; ++mi)
        #pragma unroll
        for (int ni = 0; ni < 4; ++ni)
          acc[mi][ni] = fmaf(am[mi], bn[ni], acc[mi][ni]);
    }
  }
  int crow = blockIdx.y * 64 + m0;
  int ccol = blockIdx.x * 64 + n0;
  #pragma unroll
  for (int mi = 0; mi < 4; ++mi) {
    float4 o = {1.f - acc[mi][0], 1.f - acc[mi][1],
                1.f - acc[mi][2], 1.f - acc[mi][3]};
    *(float4*)&C[(size_t)(crow + mi) * MDIM + ccol] = o;
  }
}

// ---------------- soft-DTW anti-diagonal DP ----------------
// One block per cost matrix. Diagonal d stored as vector indexed by i:
// r[d][i] = R[i, d-i]. 1024 threads, cells i = tid+1 and tid+1025.
__global__ __launch_bounds__(1024) void softdtw_dp(
    const float* __restrict__ cost_base, const float* __restrict__ gamma_p,
    float* __restrict__ partials) {
  const int M = MDIM, N = MDIM;
  int z = blockIdx.x;
  const float* cost = cost_base + (size_t)z * M * N;
  float g = fmaxf(fabsf(gamma_p[0]), 1e-4f);
  float ginv = 1.0f / g;

  __shared__ float bufA[MDIM + 1], bufB[MDIM + 1], bufC[MDIM + 1];
  float* rdm2 = bufA;
  float* rdm1 = bufB;
  float* rnew = bufC;

  int tid = threadIdx.x;
  for (int i = tid; i <= M; i += 1024) {
    bufA[i] = (i == 0) ? 0.f : BIGF;
    bufB[i] = BIGF;
    bufC[i] = BIGF;
  }
  __syncthreads();

  const int i0 = tid + 1;
  const int i1 = tid + 1 + 1024;

  // clamped cost load for cell (i, j=d-i): cost[(i-1)*N + (d-i-1)]
  auto costload = [&](int i, int d) {
    int r = i - 1, c = d - i - 1;
    r = min(max(r, 0), M - 1);
    c = min(max(c, 0), N - 1);
    return cost[(size_t)r * N + c];
  };

  float cc0 = costload(i0, 2);
  float cc1 = costload(i1, 2);

  for (int d = 2; d <= M + N; ++d) {
    // prefetch next diagonal's cost
    float cn0 = costload(i0, d + 1);
    float cn1 = costload(i1, d + 1);

    {
      int i = i0, j = d - i;
      float v = BIGF;
      if (j >= 1 && j <= N) {
        float dg = rdm2[i - 1], up = rdm1[i - 1], lf = rdm1[i];
        float mn = fminf(fminf(dg, up), lf);
        float s = __expf((mn - dg) * ginv) + __expf((mn - up) * ginv) +
                  __expf((mn - lf) * ginv);
        v = cc0 + mn - g * __logf(s);
      }
      rnew[i] = v;
    }
    {
      int i = i1, j = d - i;
      float v = BIGF;
      if (j >= 1 && j <= N) {
        float dg = rdm2[i - 1], up = rdm1[i - 1], lf = rdm1[i];
        float mn = fminf(fminf(dg, up), lf);
        float s = __expf((mn - dg) * ginv) + __expf((mn - up) * ginv) +
                  __expf((mn - lf) * ginv);
        v = cc1 + mn - g * __logf(s);
      }
      rnew[i] = v;
    }
    if (tid == 0) rnew[0] = BIGF;
    __syncthreads();
    float* t = rdm2; rdm2 = rdm1; rdm1 = rnew; rnew = t;
    cc0 = cn0; cc1 = cn1;
  }
  if (tid == 0) partials[z] = rdm1[M];  // R[M, N]
}

__global__ void combine(const float* __restrict__ partials,
                        float* __restrict__ out) {
  out[0] = partials[0] - 0.5f * (partials[1] + partials[2]);
}

extern "C" void kernel_launch(void* const* d_in, const int* in_sizes, int n_in,
                              void* d_out, int out_size, void* d_ws, size_t ws_size,
                              hipStream_t stream) {
  const float* x = (const float*)d_in[0];
  const float* y = (const float*)d_in[1];
  const float* gamma = (const float*)d_in[2];
  float* out = (float*)d_out;

  float* xn = (float*)d_ws;                       // 2048*1024
  float* yn = xn + (size_t)MDIM * KDIM;           // 2048*1024
  float* cost = yn + (size_t)MDIM * KDIM;         // 3 * 2048*2048
  float* partials = cost + (size_t)3 * MDIM * MDIM;  // 3 floats

  // 1) normalize rows of x and y (4096 waves, 4 waves/block)
  normalize_rows<<<(2 * MDIM) / 4, 256, 0, stream>>>(x, y, xn, yn);

  // 2) three cost GEMMs
  dim3 ggrid(MDIM / 64, MDIM / 64, 3);
  gemm_cost<<<ggrid, 256, 0, stream>>>(xn, yn, cost);

  // 3) three soft-DTW DPs (one block each, run concurrently)
  softdtw_dp<<<3, 1024, 0, stream>>>(cost, gamma, partials);

  // 4) combine
  combine<<<1, 1, 0, stream>>>(partials, out);
}

// Round 3
// 1134.418 us; speedup vs baseline: 5.7385x; 5.7385x over previous
//
#include <hip/hip_runtime.h>
#include <hip/hip_bf16.h>
#include <math.h>

#define MDIM 2048
#define KDIM 1024
#define BIGF 1e9f
#define KPH 64      // steps per phase
#define DELTA 144   // inter-strip skew in steps (>=143 for 16-deep prefetch safety)
#define NWAVES 16   // waves per matrix; wave wg owns strips {wg, wg+16}
#define NPH 103     // ((DELTA*31 + 2111) >> 6) + 1

// ---------------- row normalization: one wave per row ----------------
__global__ __launch_bounds__(256) void normalize_rows(
    const float* __restrict__ x, const float* __restrict__ y,
    float* __restrict__ xn, float* __restrict__ yn) {
  int wave = (blockIdx.x * blockDim.x + threadIdx.x) >> 6;
  int lane = threadIdx.x & 63;
  const float* src;
  float* dst;
  int row;
  if (wave < MDIM) { src = x; dst = xn; row = wave; }
  else             { src = y; dst = yn; row = wave - MDIM; }
  const float* r = src + (size_t)row * KDIM;
  float* w = dst + (size_t)row * KDIM;
  float ss = 0.f;
  for (int c = lane * 4; c < KDIM; c += 64 * 4) {
    float4 v = *(const float4*)&r[c];
    ss += v.x * v.x + v.y * v.y + v.z * v.z + v.w * v.w;
  }
  #pragma unroll
  for (int off = 32; off; off >>= 1) ss += __shfl_xor(ss, off, 64);
  float inv = 1.f / fmaxf(sqrtf(ss), 1e-12f);
  for (int c = lane * 4; c < KDIM; c += 64 * 4) {
    float4 v = *(const float4*)&r[c];
    float4 o = {v.x * inv, v.y * inv, v.z * inv, v.w * inv};
    *(float4*)&w[c] = o;
  }
}

// ---------------- cost GEMM: C[i][j] = 1 - dot(A_i, B_j) ----------------
__global__ __launch_bounds__(256) void gemm_cost(
    const float* __restrict__ xn, const float* __restrict__ yn,
    float* __restrict__ cost_base) {
  int z = blockIdx.z;
  const float* A = (z == 2) ? yn : xn;
  const float* B = (z == 0) ? yn : ((z == 1) ? xn : yn);
  float* C = cost_base + (size_t)z * MDIM * MDIM;

  __shared__ float As[16][64];
  __shared__ float Bs[16][64];

  int tid = threadIdx.x;
  int lrow = tid >> 2;
  int lkc  = (tid & 3) * 4;
  int m0 = (tid >> 4) * 4;
  int n0 = (tid & 15) * 4;

  float acc[4][4] = {};
  size_t arow = (size_t)(blockIdx.y * 64 + lrow) * KDIM;
  size_t brow = (size_t)(blockIdx.x * 64 + lrow) * KDIM;

  for (int k0 = 0; k0 < KDIM; k0 += 16) {
    float4 a = *(const float4*)&A[arow + k0 + lkc];
    float4 b = *(const float4*)&B[brow + k0 + lkc];
    __syncthreads();
    As[lkc + 0][lrow] = a.x; As[lkc + 1][lrow] = a.y;
    As[lkc + 2][lrow] = a.z; As[lkc + 3][lrow] = a.w;
    Bs[lkc + 0][lrow] = b.x; Bs[lkc + 1][lrow] = b.y;
    Bs[lkc + 2][lrow] = b.z; Bs[lkc + 3][lrow] = b.w;
    __syncthreads();
    #pragma unroll
    for (int k = 0; k < 16; ++k) {
      float4 av = *(const float4*)&As[k][m0];
      float4 bv = *(const float4*)&Bs[k][n0];
      float am[4] = {av.x, av.y, av.z, av.w};
      float bn[4] = {bv.x, bv.y, bv.z, bv.w};
      #pragma unroll
      for (int mi = 0; mi < 4; ++mi)
        #pragma unroll
        for (int ni = 0; ni < 4; ++ni)
          acc[mi][ni] = fmaf(am[mi], bn[ni], acc[mi][ni]);
    }
  }
  int crow = blockIdx.y * 64 + m0;
  int ccol = blockIdx.x * 64 + n0;
  #pragma unroll
  for (int mi = 0; mi < 4; ++mi) {
    float4 o = {1.f - acc[mi][0], 1.f - acc[mi][1],
                1.f - acc[mi][2], 1.f - acc[mi][3]};
    *(float4*)&C[(size_t)(crow + mi) * MDIM + ccol] = o;
  }
}

// ---------------- soft-DTW: register-pipelined wavefront ----------------
__device__ __forceinline__ float fexp2(float x) {
  return __builtin_amdgcn_exp2f(x);   // v_exp_f32: 2^x
}
__device__ __forceinline__ float flog2(float x) {
  return __builtin_amdgcn_logf(x);    // v_log_f32: log2(x)
}

__device__ __forceinline__ float dpp_shr1(float v) {
  int r = __builtin_amdgcn_update_dpp(__builtin_bit_cast(int, v),
                                      __builtin_bit_cast(int, v),
                                      0x138 /*wave_shr:1*/, 0xF, 0xF, false);
  return __builtin_bit_cast(float, r);
}

__device__ __forceinline__ float aload(const float* p) {
  return __hip_atomic_load(p, __ATOMIC_RELAXED, __HIP_MEMORY_SCOPE_AGENT);
}

struct Strip {
  float out_prev, diag_hold, res;
  float cq[16], bq[16];   // 16-deep prefetch ring queues (cost, bottom row)
  const float* crow;      // this lane's cost row base
  const float* brow;      // predecessor strip's bottom row
  float* bwr;             // this strip's bottom row (written by lane 63)
  int T;                  // start step (skew)
};

template <bool FIRST>
__device__ __forceinline__ void strip_init(Strip& st, int cstart0) {
  st.out_prev = BIGF; st.diag_hold = BIGF; st.res = BIGF;
  #pragma unroll
  for (int u = 0; u < 16; ++u) {
    int cp = min(max(cstart0 + u, 0), MDIM - 1);
    st.cq[u] = st.crow[cp];
    st.bq[u] = FIRST ? BIGF : aload(&st.brow[cp]);
  }
}

template <bool FIRST>
__device__ __forceinline__ void strip_phase(Strip& st, int p, int lane,
                                            float kexp, float glog) {
  const int cstart = p * KPH - st.T - lane;
  #pragma unroll 1
  for (int g = 0; g < 4; ++g) {
    #pragma unroll
    for (int u = 0; u < 16; ++u) {
      const int c = cstart + g * 16 + u;
      float costv = st.cq[u];
      float botv  = st.bq[u];
      // neighbor (row-1) values via in-register wave shift
      float av = dpp_shr1(st.out_prev);       // above = R[i-1][j]
      av = (lane == 0) ? (FIRST ? BIGF : botv) : av;
      float dg = st.diag_hold;                // diag = R[i-1][j-1]
      if (FIRST) dg = (lane == 0) ? ((c == 0) ? 0.0f : BIGF) : dg;
      float lf = st.out_prev;                 // left = R[i][j-1]
      float mn = fminf(fminf(dg, av), lf);
      float e = fexp2((mn - dg) * kexp) + fexp2((mn - av) * kexp) +
                fexp2((mn - lf) * kexp);
      float outv = costv + mn - glog * flog2(e);
      bool valid = (c >= 0) && (c < MDIM);
      outv = valid ? outv : BIGF;
      st.res = valid ? outv : st.res;
      if (valid && lane == 63)
        __hip_atomic_store(&st.bwr[c], outv, __ATOMIC_RELAXED,
                           __HIP_MEMORY_SCOPE_AGENT);
      st.diag_hold = av;
      st.out_prev = outv;
      // refill this slot with column c+16 (consumed 16 steps later)
      int cp = min(max(c + 16, 0), MDIM - 1);
      st.cq[u] = st.crow[cp];
      st.bq[u] = FIRST ? BIGF : aload(&st.brow[cp]);
    }
  }
}

__global__ __launch_bounds__(64) void softdtw_dp(
    const float* __restrict__ cost_base, const float* __restrict__ gamma_p,
    float* __restrict__ bottom, float* __restrict__ partials,
    int* __restrict__ flags) {
  const int wg = blockIdx.x;   // 0..15 (ring position)
  const int z  = blockIdx.y;   // matrix index
  const int lane = threadIdx.x;
  const float* cost = cost_base + (size_t)z * MDIM * MDIM;
  float* bot_z = bottom + (size_t)z * 32 * MDIM;

  float g = fmaxf(fabsf(gamma_p[0]), 1e-4f);
  float kexp = 1.44269504089f / g;   // exp(x/g)  = 2^(x*kexp)
  float glog = 0.69314718056f * g;   // g*ln(s)   = glog*log2(s)

  const int sA = wg, sB = wg + 16;
  Strip A, B;
  A.T = sA * DELTA; B.T = sB * DELTA;
  A.crow = cost + (size_t)(sA * 64 + lane) * MDIM;
  B.crow = cost + (size_t)(sB * 64 + lane) * MDIM;
  A.brow = bot_z + (size_t)max(sA - 1, 0) * MDIM;
  B.brow = bot_z + (size_t)(sB - 1) * MDIM;
  A.bwr  = bot_z + (size_t)sA * MDIM;
  B.bwr  = bot_z + (size_t)sB * MDIM;

  const int pA0 = (DELTA * sA) >> 6, pA1 = (DELTA * sA + 2111) >> 6;
  const int pB0 = (DELTA * sB) >> 6, pB1 = (DELTA * sB + 2111) >> 6;

  const int pred = (wg + NWAVES - 1) % NWAVES;
  int* predf = &flags[z * NWAVES + pred];
  int* myf   = &flags[z * NWAVES + wg];

  for (int p = 0; p < NPH; ++p) {
    // ring lockstep: wait until predecessor wave completed phase p-1
    int it = 0;
    while (__hip_atomic_load(predf, __ATOMIC_ACQUIRE,
                             __HIP_MEMORY_SCOPE_AGENT) < p) {
      __builtin_amdgcn_s_sleep(1);
      if (++it > (1 << 22)) break;  // hang guard; unreachable if protocol ok
    }
    if (p >= pA0 && p <= pA1) {
      if (wg == 0) {
        if (p == pA0) strip_init<true>(A, 64 * p - A.T - lane);
        strip_phase<true>(A, p, lane, kexp, glog);
      } else {
        if (p == pA0) strip_init<false>(A, 64 * p - A.T - lane);
        strip_phase<false>(A, p, lane, kexp, glog);
      }
    }
    if (p >= pB0 && p <= pB1) {
      if (p == pB0) strip_init<false>(B, 64 * p - B.T - lane);
      strip_phase<false>(B, p, lane, kexp, glog);
    }
    // lane 63 performed all bottom-row stores; its release orders them
    if (lane == 63)
      __hip_atomic_store(myf, p + 1, __ATOMIC_RELEASE,
                         __HIP_MEMORY_SCOPE_AGENT);
  }
  if (wg == NWAVES - 1 && lane == 63) partials[z] = B.res;  // R[M][N]
}

__global__ void dtw_init(int* __restrict__ flags) {
  if (threadIdx.x < 3 * NWAVES) flags[threadIdx.x] = 0;
}

__global__ void combine(const float* __restrict__ partials,
                        float* __restrict__ out) {
  out[0] = partials[0] - 0.5f * (partials[1] + partials[2]);
}

extern "C" void kernel_launch(void* const* d_in, const int* in_sizes, int n_in,
                              void* d_out, int out_size, void* d_ws, size_t ws_size,
                              hipStream_t stream) {
  const float* x = (const float*)d_in[0];
  const float* y = (const float*)d_in[1];
  const float* gamma = (const float*)d_in[2];
  float* out = (float*)d_out;

  float* xn = (float*)d_ws;                      // 2M floats
  float* yn = xn + (size_t)MDIM * KDIM;          // 2M floats
  float* cost = yn + (size_t)MDIM * KDIM;        // 12M floats (3 x 4M)
  // after gemm, xn region is dead -> reuse for DP scratch (stream-ordered)
  float* bottom = xn;                            // 3*32*2048 floats
  float* partials = xn + (size_t)3 * 32 * MDIM;  // 3 floats
  int* flags = (int*)(partials + 4);             // 48 ints

  normalize_rows<<<(2 * MDIM) / 4, 256, 0, stream>>>(x, y, xn, yn);

  dim3 ggrid(MDIM / 64, MDIM / 64, 3);
  gemm_cost<<<ggrid, 256, 0, stream>>>(xn, yn, cost);

  dtw_init<<<1, 64, 0, stream>>>(flags);

  dim3 dgrid(NWAVES, 3);
  softdtw_dp<<<dgrid, 64, 0, stream>>>(cost, gamma, bottom, partials, flags);

  combine<<<1, 1, 0, stream>>>(partials, out);
}

// Round 4
// 793.333 us; speedup vs baseline: 8.2056x; 1.4299x over previous
//
#include <hip/hip_runtime.h>
#include <hip/hip_bf16.h>
#include <math.h>

#define MDIM 2048
#define KDIM 1024
#define BIGF 1e9f
#define NSTRIP 16   // strips per matrix, 128 rows each (2 rows per lane)
#define DELTA 208   // inter-strip skew in steps (>= 127+16+65)
#define NPH 83      // ((DELTA*15 + 2174) >> 6) + 1

typedef unsigned short ushort;
typedef unsigned int uint;
typedef __attribute__((ext_vector_type(8))) short short8v;
typedef __attribute__((ext_vector_type(8))) ushort ushort8v;
typedef __attribute__((ext_vector_type(4))) float f32x4;

// ---------------- row normalization: one wave per row, emits bf16 ----------
__device__ __forceinline__ ushort f2bf(float f) {
  uint b = __builtin_bit_cast(uint, f);
  b += 0x7FFFu + ((b >> 16) & 1u);   // round-to-nearest-even
  return (ushort)(b >> 16);
}

__global__ __launch_bounds__(256) void normalize_rows(
    const float* __restrict__ x, const float* __restrict__ y,
    ushort* __restrict__ xb, ushort* __restrict__ yb) {
  int wave = (blockIdx.x * blockDim.x + threadIdx.x) >> 6;
  int lane = threadIdx.x & 63;
  const float* src;
  ushort* dst;
  int row;
  if (wave < MDIM) { src = x; dst = xb; row = wave; }
  else             { src = y; dst = yb; row = wave - MDIM; }
  const float* r = src + (size_t)row * KDIM;
  ushort* w = dst + (size_t)row * KDIM;
  float ss = 0.f;
  for (int c = lane * 4; c < KDIM; c += 64 * 4) {
    float4 v = *(const float4*)&r[c];
    ss += v.x * v.x + v.y * v.y + v.z * v.z + v.w * v.w;
  }
  #pragma unroll
  for (int off = 32; off; off >>= 1) ss += __shfl_xor(ss, off, 64);
  float inv = 1.f / fmaxf(sqrtf(ss), 1e-12f);
  for (int c = lane * 4; c < KDIM; c += 64 * 4) {
    float4 v = *(const float4*)&r[c];
    uint2 o;
    o.x = (uint)f2bf(v.x * inv) | ((uint)f2bf(v.y * inv) << 16);
    o.y = (uint)f2bf(v.z * inv) | ((uint)f2bf(v.w * inv) << 16);
    *(uint2*)&w[c] = o;
  }
}

// ------------- cost GEMM (bf16 MFMA): C' = (1 - A.B^T) * kexp -------------
// 128x128 tile, BK=64, 256 threads (4 waves), wave quadrant 64x64, 4x4 frags.
// LDS XOR swizzle: slot' = slot ^ (row&7)  (8 x 16B slots per 128B row).
__global__ __launch_bounds__(256) void gemm_cost_mfma(
    const ushort* __restrict__ xb, const ushort* __restrict__ yb,
    float* __restrict__ cost_base, const float* __restrict__ gamma_p) {
  int z = blockIdx.z;
  const ushort* A = (z == 2) ? yb : xb;
  const ushort* B = (z == 0) ? yb : ((z == 1) ? xb : yb);
  float* C = cost_base + (size_t)z * MDIM * MDIM;
  float g = fmaxf(fabsf(gamma_p[0]), 1e-4f);
  float kexp = 1.44269504089f / g;   // 1/(g*ln2)

  __shared__ ushort As[128 * 64];
  __shared__ ushort Bs[128 * 64];

  int tid = threadIdx.x;
  int w = tid >> 6, l = tid & 63;
  int wr = w >> 1, wc = w & 1;
  int abase = blockIdx.y * 128;
  int bbase = blockIdx.x * 128;

  f32x4 acc[4][4] = {};

  for (int k0 = 0; k0 < KDIM; k0 += 64) {
    ushort8v va[4], vb[4];
    #pragma unroll
    for (int q = 0; q < 4; ++q) {
      int slot = q * 256 + tid;
      int row = slot >> 3, sc = slot & 7;
      va[q] = *(const ushort8v*)&A[(size_t)(abase + row) * KDIM + k0 + sc * 8];
      vb[q] = *(const ushort8v*)&B[(size_t)(bbase + row) * KDIM + k0 + sc * 8];
    }
    __syncthreads();   // previous iteration's reads done
    #pragma unroll
    for (int q = 0; q < 4; ++q) {
      int slot = q * 256 + tid;
      int row = slot >> 3, sc = slot & 7;
      int off = row * 64 + ((sc ^ (row & 7)) << 3);
      *(ushort8v*)&As[off] = va[q];
      *(ushort8v*)&Bs[off] = vb[q];
    }
    __syncthreads();   // tile visible
    #pragma unroll
    for (int kk = 0; kk < 2; ++kk) {
      short8v af[4], bf[4];
      #pragma unroll
      for (int m = 0; m < 4; ++m) {
        int row = wr * 64 + m * 16 + (l & 15);
        int kg = kk * 4 + (l >> 4);
        af[m] = *(const short8v*)&As[row * 64 + ((kg ^ (row & 7)) << 3)];
      }
      #pragma unroll
      for (int n = 0; n < 4; ++n) {
        int row = wc * 64 + n * 16 + (l & 15);
        int kg = kk * 4 + (l >> 4);
        bf[n] = *(const short8v*)&Bs[row * 64 + ((kg ^ (row & 7)) << 3)];
      }
      #pragma unroll
      for (int m = 0; m < 4; ++m)
        #pragma unroll
        for (int n = 0; n < 4; ++n)
          acc[m][n] = __builtin_amdgcn_mfma_f32_16x16x32_bf16(
              af[m], bf[n], acc[m][n], 0, 0, 0);
    }
  }
  // epilogue: C' = (1 - acc) * kexp ; D layout: col=lane&15, row=(lane>>4)*4+r
  #pragma unroll
  for (int m = 0; m < 4; ++m) {
    int row0 = abase + wr * 64 + m * 16 + (l >> 4) * 4;
    #pragma unroll
    for (int n = 0; n < 4; ++n) {
      int col = bbase + wc * 64 + n * 16 + (l & 15);
      f32x4 v = acc[m][n];
      #pragma unroll
      for (int r = 0; r < 4; ++r)
        C[(size_t)(row0 + r) * MDIM + col] = (1.0f - v[r]) * kexp;
    }
  }
}

// ---------------- soft-DTW: register wavefront, 2 rows/lane ----------------
__device__ __forceinline__ float fexp2(float x) { return __builtin_amdgcn_exp2f(x); }
__device__ __forceinline__ float flog2(float x) { return __builtin_amdgcn_logf(x); }

__device__ __forceinline__ float dpp_shr1(float v) {
  int r = __builtin_amdgcn_update_dpp(__builtin_bit_cast(int, v),
                                      __builtin_bit_cast(int, v),
                                      0x138 /*wave_shr:1*/, 0xF, 0xF, false);
  return __builtin_bit_cast(float, r);
}

template <bool FIRST>
__device__ __forceinline__ void dp_phase_fast(
    float& o0, float& o1, float& d0, float& d1,
    float (&cq0)[16], float (&cq1)[16], float (&bq)[16],
    const float* c0p, const float* c1p, const float* bp, float* bw,
    int cb, int lane) {
  const bool l0 = (lane == 0);
  #pragma unroll 1
  for (int gq = 0; gq < 4; ++gq) {
    const int base = cb + gq * 16;
    const float* r0 = c0p + (base - 2 * lane + 16);
    const float* r1 = c1p + (base - 2 * lane + 15);
    const float* rb = bp + (base + 16);
    float* bwg = bw + (base - 127);
    float st[4];
    #pragma unroll
    for (int u = 0; u < 16; ++u) {
      float av0 = dpp_shr1(o1);
      av0 = l0 ? (FIRST ? BIGF : bq[u]) : av0;
      float av1 = o0;
      float mn0 = fminf(fminf(d0, av0), o0);
      float mn1 = fminf(fminf(d1, av1), o1);
      float e0 = fexp2(mn0 - d0) + fexp2(mn0 - av0) + fexp2(mn0 - o0);
      float e1 = fexp2(mn1 - d1) + fexp2(mn1 - av1) + fexp2(mn1 - o1);
      float n0 = cq0[u] + (mn0 - flog2(e0));
      float n1 = cq1[u] + (mn1 - flog2(e1));
      d0 = av0; d1 = av1; o0 = n0; o1 = n1;
      st[u & 3] = n1;
      if ((u & 3) == 3 && lane == 63) {
        float* a = bwg + (u - 3);
        a[0] = st[0]; a[1] = st[1]; a[2] = st[2]; a[3] = st[3];
      }
      cq0[u] = r0[u];
      cq1[u] = r1[u];
      bq[u] = FIRST ? BIGF : rb[u];
    }
  }
}

template <bool FIRST>
__device__ __forceinline__ void dp_phase_edge(
    float& o0, float& o1, float& d0, float& d1,
    float (&cq0)[16], float (&cq1)[16], float (&bq)[16],
    const float* c0p, const float* c1p, const float* bp, float* bw,
    int cb, int lane) {
  const bool l0 = (lane == 0);
  #pragma unroll 1
  for (int gq = 0; gq < 4; ++gq) {
    #pragma unroll
    for (int u = 0; u < 16; ++u) {
      int c0 = cb + gq * 16 + u - 2 * lane;
      int c1 = c0 - 1;
      float av0 = dpp_shr1(o1);
      if (FIRST) av0 = l0 ? ((c0 == -1) ? 0.0f : BIGF) : av0;
      else       av0 = l0 ? ((c0 < 0) ? BIGF : bq[u]) : av0;
      float av1 = o0;
      float mn0 = fminf(fminf(d0, av0), o0);
      float mn1 = fminf(fminf(d1, av1), o1);
      float e0 = fexp2(mn0 - d0) + fexp2(mn0 - av0) + fexp2(mn0 - o0);
      float e1 = fexp2(mn1 - d1) + fexp2(mn1 - av1) + fexp2(mn1 - o1);
      float n0 = cq0[u] + (mn0 - flog2(e0));
      float n1 = cq1[u] + (mn1 - flog2(e1));
      bool v0 = ((unsigned)c0 < (unsigned)MDIM);
      bool v1 = ((unsigned)c1 < (unsigned)MDIM);
      n0 = v0 ? n0 : BIGF;
      n1 = v1 ? n1 : BIGF;
      d0 = av0; d1 = av1; o0 = n0; o1 = n1;
      if (v1 && lane == 63) bw[c1] = n1;
      int q0 = min(max(c0 + 16, 0), MDIM - 1);
      int q1 = min(max(c1 + 16, 0), MDIM - 1);
      int qb = min(max(cb + gq * 16 + u + 16, 0), MDIM - 1);
      cq0[u] = c0p[q0];
      cq1[u] = c1p[q1];
      bq[u] = FIRST ? BIGF : bp[qb];
    }
  }
}

__global__ __launch_bounds__(64) void softdtw_dp(
    const float* __restrict__ cost_base, float* __restrict__ bottom,
    int* __restrict__ flags) {
  const int s = blockIdx.x;    // strip / ring position, 0..15
  const int z = blockIdx.y;    // matrix index
  const int lane = threadIdx.x;
  const float* cost = cost_base + (size_t)z * MDIM * MDIM;
  float* bot_z = bottom + (size_t)z * NSTRIP * MDIM;

  const float* c0p = cost + (size_t)(s * 128 + 2 * lane) * MDIM;
  const float* c1p = c0p + MDIM;
  const float* bp = bot_z + (size_t)((s > 0 ? s : 1) - 1) * MDIM;
  float* bw = bot_z + (size_t)s * MDIM;

  const int pS0 = (DELTA * s) >> 6;
  const int pS1 = (DELTA * s + 2174) >> 6;

  int* predf = &flags[z * NSTRIP + (s > 0 ? s - 1 : 0)];
  int* myf = &flags[z * NSTRIP + s];

  float o0 = BIGF, o1 = BIGF, d0 = BIGF, d1 = BIGF;
  float cq0[16], cq1[16], bq[16];

  for (int p = 0; p < NPH; ++p) {
    if (s > 0) {
      int it = 0;
      while (__hip_atomic_load(predf, __ATOMIC_ACQUIRE,
                               __HIP_MEMORY_SCOPE_AGENT) < p) {
        __builtin_amdgcn_s_sleep(1);
        if (++it > (1 << 22)) break;  // hang guard
      }
    }
    if (p >= pS0 && p <= pS1) {
      const int cb = 64 * p - DELTA * s;   // lane-0 col at step 0 of phase
      if (p == pS0) {
        o0 = o1 = d1 = BIGF;
        d0 = (s == 0 && lane == 0) ? 0.0f : BIGF;
        #pragma unroll
        for (int u = 0; u < 16; ++u) {
          int q0 = min(max(cb + u - 2 * lane, 0), MDIM - 1);
          int q1 = min(max(cb + u - 2 * lane - 1, 0), MDIM - 1);
          int qb = min(max(cb + u, 0), MDIM - 1);
          cq0[u] = c0p[q0];
          cq1[u] = c1p[q1];
          bq[u] = (s == 0) ? BIGF : bp[qb];
        }
      }
      bool interior = (64 * p >= DELTA * s + 127) && (64 * p <= DELTA * s + 1968);
      if (s == 0) {
        if (interior)
          dp_phase_fast<true>(o0, o1, d0, d1, cq0, cq1, bq, c0p, c1p, bp, bw, cb, lane);
        else
          dp_phase_edge<true>(o0, o1, d0, d1, cq0, cq1, bq, c0p, c1p, bp, bw, cb, lane);
      } else {
        if (interior)
          dp_phase_fast<false>(o0, o1, d0, d1, cq0, cq1, bq, c0p, c1p, bp, bw, cb, lane);
        else
          dp_phase_edge<false>(o0, o1, d0, d1, cq0, cq1, bq, c0p, c1p, bp, bw, cb, lane);
      }
    }
    if (lane == 63)
      __hip_atomic_store(myf, p + 1, __ATOMIC_RELEASE,
                         __HIP_MEMORY_SCOPE_AGENT);
  }
}

__global__ void dtw_init(int* __restrict__ flags) {
  if (threadIdx.x < 3 * NSTRIP) flags[threadIdx.x] = 0;
}

__global__ void combine(const float* __restrict__ bottom,
                        const float* __restrict__ gamma_p,
                        float* __restrict__ out) {
  float g = fmaxf(fabsf(gamma_p[0]), 1e-4f);
  float glog = 0.69314718056f * g;   // unscale: V = V' * g * ln2
  float b0 = bottom[0 * NSTRIP * MDIM + 15 * MDIM + 2047];
  float b1 = bottom[1 * NSTRIP * MDIM + 15 * MDIM + 2047];
  float b2 = bottom[2 * NSTRIP * MDIM + 15 * MDIM + 2047];
  out[0] = (b0 - 0.5f * (b1 + b2)) * glog;
}

extern "C" void kernel_launch(void* const* d_in, const int* in_sizes, int n_in,
                              void* d_out, int out_size, void* d_ws, size_t ws_size,
                              hipStream_t stream) {
  const float* x = (const float*)d_in[0];
  const float* y = (const float*)d_in[1];
  const float* gamma = (const float*)d_in[2];
  float* out = (float*)d_out;

  // workspace layout (bytes)
  char* ws = (char*)d_ws;
  ushort* xb = (ushort*)ws;                               // 4 MB
  ushort* yb = (ushort*)(ws + (size_t)4 * 1024 * 1024);   // 4 MB
  float* cost = (float*)(ws + (size_t)8 * 1024 * 1024);   // 48 MB
  float* bottom = (float*)(ws + (size_t)56 * 1024 * 1024);// 384 KB
  int* flags = (int*)(ws + (size_t)57 * 1024 * 1024);     // 192 B

  normalize_rows<<<(2 * MDIM) / 4, 256, 0, stream>>>(x, y, xb, yb);

  dim3 ggrid(MDIM / 128, MDIM / 128, 3);
  gemm_cost_mfma<<<ggrid, 256, 0, stream>>>(xb, yb, cost, gamma);

  dtw_init<<<1, 64, 0, stream>>>(flags);

  dim3 dgrid(NSTRIP, 3);
  softdtw_dp<<<dgrid, 64, 0, stream>>>(cost, bottom, flags);

  combine<<<1, 1, 0, stream>>>(bottom, gamma, out);
}